// Round 10
// baseline (3645.693 us; speedup 1.0000x reference)
//
#include <hip/hip_runtime.h>

// LSTM char-RNN forward: batch=1024, T=512, UNITS=256, NUM_CHARS=128.
// R10: exchange-free. 64 blocks x 512 threads (8 waves, 2/SIMD); each block
// owns 16 rows x ALL 256 units -> the recurrence is block-local (h lives in
// double-buffered LDS A-frags; ONE barrier/step; no inter-block protocol).
// Weights per wave (8 n-tiles): 2 tiles reg-pinned, 6 tiles streamed from
// L2 each step (no h-dependency -> pure prefetchable bandwidth, double-
// buffered regs, opaque-zero offset defeats LICM). Gates via per-wave
// private LDS scratch (stride-20 pad). Same fp16 weights / fp32 z math as
// R8 -> absmax ~6e-5.

#define TSTEPS 512
#define UNITS  256
#define NCHAR  128
#define G4     1024
#define SCRS   20                 // scratch row stride (floats); 80 B, 16B-aligned
#define SCRW   (16 * SCRS)        // floats per wave

typedef float    f32x4 __attribute__((ext_vector_type(4)));
typedef _Float16 f16x8 __attribute__((ext_vector_type(8)));

union FU { uint4 u4; f16x8 h8; _Float16 h[8]; };

__device__ __forceinline__ float fast_rcp(float x) {
#if __has_builtin(__builtin_amdgcn_rcpf)
  return __builtin_amdgcn_rcpf(x);
#else
  return 1.0f / x;
#endif
}
__device__ __forceinline__ float sigm(float x)  { return fast_rcp(1.0f + __expf(-x)); }
__device__ __forceinline__ float tanhx(float x) { return 2.0f * fast_rcp(1.0f + __expf(-2.0f * x)) - 1.0f; }

// ---- Prep: WhB = Wh fp16 B-fragment stream (UNCHANGED from R8, proven).
// Global tile T = cc*32+tile in 0..63; n = tile*16+(l&15); gate = n&3;
// col = gate*256 + cc*128 + (n>>2); k = kk*32 + (l>>4)*8 + j.
__global__ void prep_whB(const float* __restrict__ Wh, uint4* __restrict__ WhB) {
  int idx = blockIdx.x * blockDim.x + threadIdx.x;    // 0..32767
  int l    = idx & 63;
  int kk   = (idx >> 6) & 7;
  int tile = (idx >> 9) & 31;
  int cc   = idx >> 14;
  int n    = tile * 16 + (l & 15);
  int gate = n & 3;
  int col  = gate * 256 + cc * 128 + (n >> 2);
  int kb   = kk * 32 + (l >> 4) * 8;
  FU p;
#pragma unroll
  for (int j = 0; j < 8; ++j)
    p.h[j] = (_Float16)Wh[(kb + j) * G4 + col];
  WhB[idx] = p.u4;
}

// ---- Prep: Wxbg[ch][u] = float4(i,f,g,o) = Wx[ch][gate*256+u] + b (unchanged)
__global__ void prep_wx(const float* __restrict__ Wx, const float* __restrict__ bias,
                        float4* __restrict__ Wxbg) {
  int idx = blockIdx.x * blockDim.x + threadIdx.x;    // 0..32767
  int u  = idx & (UNITS - 1);
  int ch = idx >> 8;
  const float* r = Wx + ch * G4;
  float4 o;
  o.x = r[0 * UNITS + u] + bias[0 * UNITS + u];
  o.y = r[1 * UNITS + u] + bias[1 * UNITS + u];
  o.z = r[2 * UNITS + u] + bias[2 * UNITS + u];
  o.w = r[3 * UNITS + u] + bias[3 * UNITS + u];
  Wxbg[idx] = o;
}

// A-frag LDS byte address for h element (row m, k). (R8-proven layout:
// addr = kk*1024 + lane*16 + j*2 for k = kk*32+(lane>>4)*8+j, m = lane&15.)
__device__ __forceinline__ int afrag_addr(int k, int m) {
  return ((k >> 5) << 10) + (((((k >> 3) & 3) << 4) + m) << 4) + ((k & 7) << 1);
}

// One n-tile: MFMA over K=256 (8 chained kk), z->per-wave scratch, gates,
// h -> write-buffer A-frags. All in-wave except the global xb prefetch.
#define DO_TILE(i, WARR)                                                       \
  {                                                                            \
    f32x4 acc = {0.f, 0.f, 0.f, 0.f};                                          \
    _Pragma("unroll")                                                          \
    for (int kk = 0; kk < 8; ++kk)                                             \
      acc = __builtin_amdgcn_mfma_f32_16x16x32_f16(A[kk].h8, WARR[kk].h8,      \
                                                   acc, 0, 0, 0);              \
    _Pragma("unroll")                                                          \
    for (int reg = 0; reg < 4; ++reg)                                          \
      scr[(cq * 4 + reg) * SCRS + cn] = acc[reg];                              \
    float4 zv = *(const float4*)&scr[r * SCRS + u4 * 4];                       \
    float iv = sigm(zv.x + xb.x), fv = sigm(zv.y + xb.y);                      \
    float gv = tanhx(zv.z + xb.z), ov = sigm(zv.w + xb.w);                     \
    c[i] = fv * c[i] + iv * gv;                                                \
    float hv = ov * tanhx(c[i]);                                               \
    *(_Float16*)(hb_w + hoff[i]) = (_Float16)hv;                               \
    xb = xbn;                                                                  \
    if ((i) < 6) xbn = Wxbg[ch * 256 + unit[(i) + 2]];                         \
  }

// ---- Main: 64 blocks x 512 threads (8 waves).
__global__ __launch_bounds__(512, 2) void lstm_full(
    const int* __restrict__ inp, const uint4* __restrict__ WhB,
    const float4* __restrict__ Wxbg, const float* __restrict__ Wd,
    const float* __restrict__ bd, float* __restrict__ out) {
  __shared__ __align__(16) uint4 hfrag[2][512];       // 16 KB, dbuf A-frags
  __shared__ __align__(16) float scratch[8 * SCRW];   // 10 KB, per-wave z
  __shared__ float zbufE[16 * 264];                   // 16.9 KB (epilogue)
  __shared__ float lgts[16 * 132];                    // 8.4 KB
  __shared__ float rmax[16], rsum[16];

  const int tid  = threadIdx.x;
  const int lane = tid & 63;
  const int wv   = tid >> 6;        // 0..7
  const int g    = blockIdx.x;      // 0..63 row-group
  const int row0 = g * 16;
  const int T0   = wv * 8;          // this wave's 8 tiles

  const int cq = lane >> 4, cn = lane & 15;   // MFMA C-layout coords
  const int r  = lane & 15;                   // gate row
  const int u4 = lane >> 4;                   // unit-quad 0..3

  int unit[8], hoff[8];
#pragma unroll
  for (int i = 0; i < 8; ++i) {
    int T = T0 + i;
    unit[i] = ((T >> 5) << 7) + ((T & 31) << 2) + u4;
    hoff[i] = afrag_addr(unit[i], r);
  }

  // ---- reg-resident weights: tiles T0+0, T0+1 (pinned; R4/R5-proven)
  FU w0[8], w1[8];
#pragma unroll
  for (int kk = 0; kk < 8; ++kk) {
    w0[kk].u4 = WhB[((T0 + 0) * 8 + kk) * 64 + lane];
    w1[kk].u4 = WhB[((T0 + 1) * 8 + kk) * 64 + lane];
  }
#pragma unroll
  for (int kk = 0; kk < 8; ++kk) {
    asm volatile("" : "+v"(w0[kk].u4.x), "+v"(w0[kk].u4.y), "+v"(w0[kk].u4.z), "+v"(w0[kk].u4.w));
    asm volatile("" : "+v"(w1[kk].u4.x), "+v"(w1[kk].u4.y), "+v"(w1[kk].u4.z), "+v"(w1[kk].u4.w));
  }

  hfrag[0][tid] = uint4{0u, 0u, 0u, 0u};   // h_0 = 0 (512 entries exactly)
  float c[8] = {0.f, 0.f, 0.f, 0.f, 0.f, 0.f, 0.f, 0.f};
  float* scr = &scratch[wv * SCRW];
  __syncthreads();

  for (int t = 0; t < TSTEPS; ++t) {
    const int p = t & 1;
    char* hb_w = (char*)hfrag[1 - p];

    // opaque zero: stream-load addresses look t-dependent -> no LICM hoist
    int zoff = 0;
    asm volatile("" : "+v"(zoff));

    // A-frags for this step (shared across all 8 tiles)
    FU A[8];
#pragma unroll
    for (int kk = 0; kk < 8; ++kk) A[kk].u4 = hfrag[p][kk * 64 + lane];

    const int ch = inp[(row0 + r) * TSTEPS + t];

    // stream buffers: issue tiles T0+2, T0+3 now; reissue 2-ahead below
    FU wsA[8], wsB[8];
#pragma unroll
    for (int kk = 0; kk < 8; ++kk)
      wsA[kk].u4 = WhB[((T0 + 2) * 8 + kk) * 64 + lane + zoff];
#pragma unroll
    for (int kk = 0; kk < 8; ++kk)
      wsB[kk].u4 = WhB[((T0 + 3) * 8 + kk) * 64 + lane + zoff];

    float4 xb  = Wxbg[ch * 256 + unit[0]];
    float4 xbn = Wxbg[ch * 256 + unit[1]];

    DO_TILE(0, w0)
    DO_TILE(1, w1)
    DO_TILE(2, wsA)
#pragma unroll
    for (int kk = 0; kk < 8; ++kk)
      wsA[kk].u4 = WhB[((T0 + 4) * 8 + kk) * 64 + lane + zoff];
    DO_TILE(3, wsB)
#pragma unroll
    for (int kk = 0; kk < 8; ++kk)
      wsB[kk].u4 = WhB[((T0 + 5) * 8 + kk) * 64 + lane + zoff];
    DO_TILE(4, wsA)
#pragma unroll
    for (int kk = 0; kk < 8; ++kk)
      wsA[kk].u4 = WhB[((T0 + 6) * 8 + kk) * 64 + lane + zoff];
    DO_TILE(5, wsB)
#pragma unroll
    for (int kk = 0; kk < 8; ++kk)
      wsB[kk].u4 = WhB[((T0 + 7) * 8 + kk) * 64 + lane + zoff];
    DO_TILE(6, wsA)
    DO_TILE(7, wsB)

    __syncthreads();   // h(t+1) A-frags complete; the ONLY barrier per step
  }

  // ---- Epilogue (every block, own 16 rows). h_T is in hfrag[0] (T even).
  {
    const int rr = tid & 15, K8 = tid >> 4;   // K8 0..31
    FU v;
    v.u4 = *(const uint4*)((const char*)hfrag[0] + afrag_addr(K8 * 8, rr));
#pragma unroll
    for (int jj = 0; jj < 8; ++jj)
      zbufE[rr * 264 + K8 * 8 + jj] = (float)v.h[jj];
  }
  __syncthreads();
  {
    const int j = tid & 127, rb = tid >> 7;   // rb 0..3 -> rows rb*4..+3
    float l[4];
#pragma unroll
    for (int ii = 0; ii < 4; ++ii) l[ii] = bd[j];
    for (int k = 0; k < 256; ++k) {
      float w = Wd[k * NCHAR + j];
#pragma unroll
      for (int ii = 0; ii < 4; ++ii)
        l[ii] += zbufE[(rb * 4 + ii) * 264 + k] * w;
    }
#pragma unroll
    for (int ii = 0; ii < 4; ++ii) lgts[(rb * 4 + ii) * 132 + j] = l[ii];
  }
  __syncthreads();
  if (tid < 16) {
    const int rr = tid;
    float m = -1e30f;
    for (int j = 0; j < NCHAR; ++j) m = fmaxf(m, lgts[rr * 132 + j]);
    float s = 0.f;
    for (int j = 0; j < NCHAR; ++j) s += __expf(lgts[rr * 132 + j] - m);
    rmax[rr] = m;
    rsum[rr] = fast_rcp(s);
  }
  __syncthreads();
  {
    const int j = tid & 127, rb = tid >> 7;
#pragma unroll
    for (int ii = 0; ii < 4; ++ii) {
      int rr = rb * 4 + ii;
      out[(row0 + rr) * NCHAR + j] =
          __expf(lgts[rr * 132 + j] - rmax[rr]) * rsum[rr];
    }
  }
}

extern "C" void kernel_launch(void* const* d_in, const int* in_sizes, int n_in,
                              void* d_out, int out_size, void* d_ws, size_t ws_size,
                              hipStream_t stream) {
  const int*   inp = (const int*)d_in[0];
  const float* Wx  = (const float*)d_in[1];
  const float* Wh  = (const float*)d_in[2];
  const float* bia = (const float*)d_in[3];
  const float* Wd  = (const float*)d_in[4];
  const float* bd  = (const float*)d_in[5];

  uint4*  WhB  = (uint4*)d_ws;                           // 512 KB
  float4* Wxbg = (float4*)((char*)d_ws + (512 << 10));   // 512 KB

  prep_whB<<<128, 256, 0, stream>>>(Wh, WhB);
  prep_wx<<<128, 256, 0, stream>>>(Wx, bia, Wxbg);
  lstm_full<<<64, 512, 0, stream>>>(inp, WhB, Wxbg, Wd, bd, (float*)d_out);
}

// Round 11
// 1989.675 us; speedup vs baseline: 1.8323x; 1.8323x over previous
//
#include <hip/hip_runtime.h>

// LSTM char-RNN forward: batch=1024, T=512, UNITS=256, NUM_CHARS=128.
// R11: block-local recurrence (no inter-block protocol) with ALL weights
// on-chip: per wave 6 tiles pinned in registers (192 regs, AGPR-backed;
// R4/R8-proven) + 2 tiles static in LDS (128 KB). 64 blocks x 512 threads;
// block owns 16 rows x all 256 units; h single-buffered in LDS A-frags,
// 2 barriers/step. Tiles processed as 4 pairs (interleaved MFMA chains --
// fixes R10's serial-chain disease; R10's in-loop L2 streaming removed).
// Same kk accumulation order as R8 -> absmax 6.1e-5.

#define TSTEPS 512
#define UNITS  256
#define NCHAR  128
#define G4     1024
#define SCRS   36     // scratch row stride (floats): 144 B, 16B-aligned

typedef float    f32x4 __attribute__((ext_vector_type(4)));
typedef _Float16 f16x8 __attribute__((ext_vector_type(8)));

union FU { uint4 u4; f16x8 h8; _Float16 h[8]; };

__device__ __forceinline__ float fast_rcp(float x) {
#if __has_builtin(__builtin_amdgcn_rcpf)
  return __builtin_amdgcn_rcpf(x);
#else
  return 1.0f / x;
#endif
}
__device__ __forceinline__ float sigm(float x)  { return fast_rcp(1.0f + __expf(-x)); }
__device__ __forceinline__ float tanhx(float x) { return 2.0f * fast_rcp(1.0f + __expf(-2.0f * x)) - 1.0f; }

// ---- Prep: WhB = Wh fp16 B-fragment stream (R8-proven, unchanged).
// T = cc*32+tile in 0..63; n = tile*16+(l&15); gate = n&3;
// col = gate*256 + cc*128 + (n>>2); k = kk*32 + (l>>4)*8 + j.
__global__ void prep_whB(const float* __restrict__ Wh, uint4* __restrict__ WhB) {
  int idx = blockIdx.x * blockDim.x + threadIdx.x;    // 0..32767
  int l    = idx & 63;
  int kk   = (idx >> 6) & 7;
  int tile = (idx >> 9) & 31;
  int cc   = idx >> 14;
  int n    = tile * 16 + (l & 15);
  int gate = n & 3;
  int col  = gate * 256 + cc * 128 + (n >> 2);
  int kb   = kk * 32 + (l >> 4) * 8;
  FU p;
#pragma unroll
  for (int j = 0; j < 8; ++j)
    p.h[j] = (_Float16)Wh[(kb + j) * G4 + col];
  WhB[idx] = p.u4;
}

// ---- Prep: Wxbg[ch][u] = float4(i,f,g,o) = Wx[ch][gate*256+u] + b
__global__ void prep_wx(const float* __restrict__ Wx, const float* __restrict__ bias,
                        float4* __restrict__ Wxbg) {
  int idx = blockIdx.x * blockDim.x + threadIdx.x;    // 0..32767
  int u  = idx & (UNITS - 1);
  int ch = idx >> 8;
  const float* r = Wx + ch * G4;
  float4 o;
  o.x = r[0 * UNITS + u] + bias[0 * UNITS + u];
  o.y = r[1 * UNITS + u] + bias[1 * UNITS + u];
  o.z = r[2 * UNITS + u] + bias[2 * UNITS + u];
  o.w = r[3 * UNITS + u] + bias[3 * UNITS + u];
  Wxbg[idx] = o;
}

// A-frag LDS byte address for h element (row m, k). (R8-proven layout.)
__device__ __forceinline__ int afrag_addr(int k, int m) {
  return ((k >> 5) << 10) + (((((k >> 3) & 3) << 4) + m) << 4) + ((k & 7) << 1);
}

// ---- Main: 64 blocks x 512 threads (8 waves, 2/SIMD -> 256 regs/wave).
__global__ __launch_bounds__(512, 2) void lstm_local(
    const int* __restrict__ inp, const uint4* __restrict__ WhB,
    const float4* __restrict__ Wxbg, const float* __restrict__ Wd,
    const float* __restrict__ bd, float* __restrict__ out) {
  __shared__ __align__(16) uint4 wlds[16 * 512];              // 131072 B: 16 tile-slots
  __shared__ __align__(16) uint4 hfrag[512];                  // 8192 B: h A-frags
  __shared__ __align__(16) float scratch[8 * 16 * SCRS];      // 18432 B: per-wave z
  // total 157,696 B; epilogue aliases wlds (weights dead after t-loop)

  const int tid  = threadIdx.x;
  const int lane = tid & 63;
  const int wv   = tid >> 6;        // 0..7
  const int g    = blockIdx.x;      // row-group
  const int row0 = g * 16;
  const int T0   = wv * 8;          // this wave's 8 tiles

  const int cq = lane >> 4, cn = lane & 15;   // MFMA C coords
  const int r  = lane & 15;                   // gate row
  const int u4 = lane >> 4;                   // unit-quad within tile
  // unit for tile T0+i at this thread = unit0 + 4*i  (derivation: T=8wv+i,
  // unit = ((T>>5)<<7) + ((T&31)<<2) + u4; 8wv+i never crosses a 32-block)
  const int unit0 = ((wv >> 2) << 7) + ((wv & 3) << 5) + u4;

  // ---- pinned weights: tiles T0..T0+5 (192 regs -> AGPR-backed)
  FU wp[6][8];
#pragma unroll
  for (int i = 0; i < 6; ++i)
#pragma unroll
    for (int kk = 0; kk < 8; ++kk)
      wp[i][kk].u4 = WhB[((T0 + i) * 8 + kk) * 64 + lane];
#pragma unroll
  for (int i = 0; i < 6; ++i)
#pragma unroll
    for (int kk = 0; kk < 8; ++kk)
      asm volatile("" : "+v"(wp[i][kk].u4.x), "+v"(wp[i][kk].u4.y),
                        "+v"(wp[i][kk].u4.z), "+v"(wp[i][kk].u4.w));

  // ---- LDS weights: tiles T0+6, T0+7 -> slots 2wv, 2wv+1
#pragma unroll
  for (int d = 0; d < 2; ++d)
#pragma unroll
    for (int kk = 0; kk < 8; ++kk)
      wlds[(2 * wv + d) * 512 + kk * 64 + lane] =
          WhB[((T0 + 6 + d) * 8 + kk) * 64 + lane];

  hfrag[tid] = uint4{0u, 0u, 0u, 0u};   // h_0 = 0
  float c[8] = {0.f, 0.f, 0.f, 0.f, 0.f, 0.f, 0.f, 0.f};
  float* scr = &scratch[wv * 16 * SCRS];
  __syncthreads();

  for (int t = 0; t < TSTEPS; ++t) {
    // read h(t) A-frags into regs (shared by all 8 tiles)
    FU A[8];
#pragma unroll
    for (int kk = 0; kk < 8; ++kk) A[kk].u4 = hfrag[kk * 64 + lane];
    const int ch = inp[(row0 + r) * TSTEPS + t];
    int wb = (2 * wv) * 512;
    asm volatile("" : "+v"(wb));   // block hoisting of weight ds_reads
    __syncthreads();               // all h(t) reads done -> hfrag writable

    // ---- 4 tile-pairs: interleaved MFMA chains, z->scratch, gates, h-write
#pragma unroll
    for (int pr = 0; pr < 4; ++pr) {
      const int ta = 2 * pr, tb = 2 * pr + 1;
      float4 xba = Wxbg[ch * 256 + unit0 + 4 * ta];
      float4 xbb = Wxbg[ch * 256 + unit0 + 4 * tb];

      f32x4 acc0 = {0.f, 0.f, 0.f, 0.f}, acc1 = {0.f, 0.f, 0.f, 0.f};
      if (pr < 3) {
#pragma unroll
        for (int kk = 0; kk < 8; ++kk) {
          acc0 = __builtin_amdgcn_mfma_f32_16x16x32_f16(A[kk].h8, wp[ta][kk].h8, acc0, 0, 0, 0);
          acc1 = __builtin_amdgcn_mfma_f32_16x16x32_f16(A[kk].h8, wp[tb][kk].h8, acc1, 0, 0, 0);
        }
      } else {
#pragma unroll
        for (int kk = 0; kk < 8; ++kk) {
          FU b0, b1;
          b0.u4 = wlds[wb + kk * 64 + lane];
          b1.u4 = wlds[wb + 512 + kk * 64 + lane];
          acc0 = __builtin_amdgcn_mfma_f32_16x16x32_f16(A[kk].h8, b0.h8, acc0, 0, 0, 0);
          acc1 = __builtin_amdgcn_mfma_f32_16x16x32_f16(A[kk].h8, b1.h8, acc1, 0, 0, 0);
        }
      }
      // z -> scratch: tile ta cols 0..15, tile tb cols 16..31 (stride 36)
#pragma unroll
      for (int reg = 0; reg < 4; ++reg) {
        scr[(cq * 4 + reg) * SCRS + cn]      = acc0[reg];
        scr[(cq * 4 + reg) * SCRS + 16 + cn] = acc1[reg];
      }
      // gates (in-wave lgkm ordering; no barrier needed)
      {
        float4 z0 = *(const float4*)&scr[r * SCRS + u4 * 4];
        float4 z1 = *(const float4*)&scr[r * SCRS + 16 + u4 * 4];
        float i0 = sigm(z0.x + xba.x), f0 = sigm(z0.y + xba.y);
        float g0 = tanhx(z0.z + xba.z), o0 = sigm(z0.w + xba.w);
        c[ta] = f0 * c[ta] + i0 * g0;
        float ha = o0 * tanhx(c[ta]);
        float i1 = sigm(z1.x + xbb.x), f1 = sigm(z1.y + xbb.y);
        float g1 = tanhx(z1.z + xbb.z), o1 = sigm(z1.w + xbb.w);
        c[tb] = f1 * c[tb] + i1 * g1;
        float hb = o1 * tanhx(c[tb]);
        *(_Float16*)((char*)hfrag + afrag_addr(unit0 + 4 * ta, r)) = (_Float16)ha;
        *(_Float16*)((char*)hfrag + afrag_addr(unit0 + 4 * tb, r)) = (_Float16)hb;
      }
    }
    __syncthreads();   // h(t+1) complete
  }

  // ---- Epilogue (own 16 rows). h_T in hfrag; reuse wlds space.
  float* zbufE = (float*)wlds;            // [16][264]
  float* lgts  = zbufE + 16 * 264;        // [16][132]
  float* rmax  = lgts + 16 * 132;         // [16]
  float* rsum  = rmax + 16;               // [16]
  {
    const int rr = tid & 15, K8 = tid >> 4;   // K8 0..31
    FU v;
    v.u4 = *(const uint4*)((const char*)hfrag + afrag_addr(K8 * 8, rr));
#pragma unroll
    for (int jj = 0; jj < 8; ++jj)
      zbufE[rr * 264 + K8 * 8 + jj] = (float)v.h[jj];
  }
  __syncthreads();
  {
    const int j = tid & 127, rb = tid >> 7;   // rb 0..3 -> rows rb*4..+3
    float l[4];
#pragma unroll
    for (int ii = 0; ii < 4; ++ii) l[ii] = bd[j];
    for (int k = 0; k < 256; ++k) {
      float w = Wd[k * NCHAR + j];
#pragma unroll
      for (int ii = 0; ii < 4; ++ii)
        l[ii] += zbufE[(rb * 4 + ii) * 264 + k] * w;
    }
#pragma unroll
    for (int ii = 0; ii < 4; ++ii) lgts[(rb * 4 + ii) * 132 + j] = l[ii];
  }
  __syncthreads();
  if (tid < 16) {
    const int rr = tid;
    float m = -1e30f;
    for (int j = 0; j < NCHAR; ++j) m = fmaxf(m, lgts[rr * 132 + j]);
    float s = 0.f;
    for (int j = 0; j < NCHAR; ++j) s += __expf(lgts[rr * 132 + j] - m);
    rmax[rr] = m;
    rsum[rr] = fast_rcp(s);
  }
  __syncthreads();
  {
    const int j = tid & 127, rb = tid >> 7;
#pragma unroll
    for (int ii = 0; ii < 4; ++ii) {
      int rr = rb * 4 + ii;
      out[(row0 + rr) * NCHAR + j] =
          __expf(lgts[rr * 132 + j] - rmax[rr]) * rsum[rr];
    }
  }
}

extern "C" void kernel_launch(void* const* d_in, const int* in_sizes, int n_in,
                              void* d_out, int out_size, void* d_ws, size_t ws_size,
                              hipStream_t stream) {
  const int*   inp = (const int*)d_in[0];
  const float* Wx  = (const float*)d_in[1];
  const float* Wh  = (const float*)d_in[2];
  const float* bia = (const float*)d_in[3];
  const float* Wd  = (const float*)d_in[4];
  const float* bd  = (const float*)d_in[5];

  uint4*  WhB  = (uint4*)d_ws;                           // 512 KB
  float4* Wxbg = (float4*)((char*)d_ws + (512 << 10));   // 512 KB

  prep_whB<<<128, 256, 0, stream>>>(Wh, WhB);
  prep_wx<<<128, 256, 0, stream>>>(Wx, bia, Wxbg);
  lstm_local<<<64, 512, 0, stream>>>(inp, WhB, Wxbg, Wd, bd, (float*)d_out);
}

// Round 12
// 1108.028 us; speedup vs baseline: 3.2903x; 1.7957x over previous
//
#include <hip/hip_runtime.h>

// LSTM char-RNN forward: batch=1024, T=512, UNITS=256, NUM_CHARS=128.
// R12 = R8 (1097us, the cross-XCD-safe floor) with the exchange read path
// upgraded: producer publishes tagged u64 words with agent-scope stores
// (write-through to the coherence point -> cross-XCD correct; updates the
// local/shared XCD L2 en route). Consumer polls with an sc0-only load
// (L1-bypass, served by the shared L2: ~250cyc instead of ~900), escalating
// to an agent-scope load every 8th retry (liveness under ANY placement or
// write-around behavior -- tag validation makes stale reads harmless).
// No XCD detection, no path choice, no split-brain. Same arithmetic as R8
// -> absmax exactly 6.1e-5.

#define TSTEPS 512
#define UNITS  256
#define NCHAR  128
#define G4     1024
#define ZS     516   // zbuf row stride

typedef float    f32x4 __attribute__((ext_vector_type(4)));
typedef _Float16 f16x8 __attribute__((ext_vector_type(8)));

union FU { uint4 u4; f16x8 h8; _Float16 h[8]; };
union HP { unsigned int u; _Float16 f[2]; };

__device__ __forceinline__ float fast_rcp(float x) {
#if __has_builtin(__builtin_amdgcn_rcpf)
  return __builtin_amdgcn_rcpf(x);
#else
  return 1.0f / x;
#endif
}
__device__ __forceinline__ float sigm(float x)  { return fast_rcp(1.0f + __expf(-x)); }
__device__ __forceinline__ float tanhx(float x) { return 2.0f * fast_rcp(1.0f + __expf(-2.0f * x)) - 1.0f; }

// L1-bypassing 8B load served by the (shared, same-XCD) L2. Blocking.
__device__ __forceinline__ unsigned long long load_l2_u64(
    const unsigned long long* p) {
  unsigned long long v;
  asm volatile("global_load_dwordx2 %0, %1, off sc0\n\t"
               "s_waitcnt vmcnt(0)"
               : "=v"(v) : "v"(p) : "memory");
  return v;
}

// Tag-validated poll: fast L2 loads, agent-scope escalation every 8th try.
__device__ __forceinline__ unsigned long long poll_tagged(
    const unsigned long long* src, unsigned want) {
  unsigned long long v;
  long tries = 0;
  do {
    if ((tries & 7) == 7)
      v = __hip_atomic_load(src, __ATOMIC_RELAXED, __HIP_MEMORY_SCOPE_AGENT);
    else
      v = load_l2_u64(src);
  } while ((unsigned)(v >> 32) != want && ++tries < (1L << 18));
  return v;
}

// ---- Prep: WhB = Wh fp16 B-fragment stream (R8-proven, unchanged).
__global__ void prep_whB(const float* __restrict__ Wh, uint4* __restrict__ WhB) {
  int idx = blockIdx.x * blockDim.x + threadIdx.x;    // 0..32767
  int l    = idx & 63;
  int kk   = (idx >> 6) & 7;
  int tile = (idx >> 9) & 31;
  int cc   = idx >> 14;
  int n    = tile * 16 + (l & 15);
  int gate = n & 3;
  int col  = gate * 256 + cc * 128 + (n >> 2);
  int kb   = kk * 32 + (l >> 4) * 8;
  FU p;
#pragma unroll
  for (int j = 0; j < 8; ++j)
    p.h[j] = (_Float16)Wh[(kb + j) * G4 + col];
  WhB[idx] = p.u4;
}

// ---- Prep: Wxbg[ch][u] = float4(i,f,g,o) = Wx[ch][gate*256+u] + b
__global__ void prep_wx(const float* __restrict__ Wx, const float* __restrict__ bias,
                        float4* __restrict__ Wxbg) {
  int idx = blockIdx.x * blockDim.x + threadIdx.x;    // 0..32767
  int u  = idx & (UNITS - 1);
  int ch = idx >> 8;
  const float* r = Wx + ch * G4;
  float4 o;
  o.x = r[0 * UNITS + u] + bias[0 * UNITS + u];
  o.y = r[1 * UNITS + u] + bias[1 * UNITS + u];
  o.z = r[2 * UNITS + u] + bias[2 * UNITS + u];
  o.w = r[3 * UNITS + u] + bias[3 * UNITS + u];
  Wxbg[idx] = o;
}

// A-frag LDS byte address for h element (row m, k).
__device__ __forceinline__ int afrag_addr(int k, int m) {
  return ((k >> 5) << 10) + (((((k >> 3) & 3) << 4) + m) << 4) + ((k & 7) << 1);
}

// ---- Main: 128 blocks x 1024 threads. (g = bid&63, c = bid>>6).
__global__ __launch_bounds__(1024) void lstm_mfma(
    const int* __restrict__ inp, const uint4* __restrict__ WhB,
    const float4* __restrict__ Wxbg, const float* __restrict__ Wd,
    const float* __restrict__ bd, float* __restrict__ out,
    unsigned long long* __restrict__ hx2) {
  __shared__ __align__(16) uint4 hfrag[512];     // 8 KB: h_t A-frags (K=256)
  __shared__ float zbuf[16 * ZS];                // 33 KB
  __shared__ float lgts[16 * 132];               // 8.4 KB
  __shared__ float rmax[16], rsum[16];

  const int tid  = threadIdx.x;
  const int lane = tid & 63;
  const int wv   = tid >> 6;          // 0..15 == batch row within group
  const int bid  = blockIdx.x;
  const int g    = bid & 63;
  const int c    = bid >> 6;          // column half
  const int row0 = g * 16;

  // ---- Weight B-frags, own-half kk's in slots 0..3, sibling-half in 4..7.
  FU wf0[8], wf1[8];
#pragma unroll
  for (int kx = 0; kx < 8; ++kx) {
    int kk = (kx < 4) ? (c * 4 + kx) : ((1 - c) * 4 + (kx - 4));
    wf0[kx].u4 = WhB[((c * 32 + wv * 2)     * 8 + kk) * 64 + lane];
    wf1[kx].u4 = WhB[((c * 32 + wv * 2 + 1) * 8 + kk) * 64 + lane];
  }
#pragma unroll
  for (int kx = 0; kx < 8; ++kx) {
    asm volatile("" : "+v"(wf0[kx].u4.x), "+v"(wf0[kx].u4.y), "+v"(wf0[kx].u4.z), "+v"(wf0[kx].u4.w));
    asm volatile("" : "+v"(wf1[kx].u4.x), "+v"(wf1[kx].u4.y), "+v"(wf1[kx].u4.z), "+v"(wf1[kx].u4.w));
  }

  if (tid < 512) hfrag[tid] = uint4{0u, 0u, 0u, 0u};   // h_0 = 0
  float cst0 = 0.f, cst1 = 0.f;
  __syncthreads();
  const int kown = c * 4, ksib = (1 - c) * 4;
  const int cs   = 1 - c;

  for (int t = 0; t < TSTEPS; ++t) {
    int    ch  = inp[(row0 + wv) * TSTEPS + t];
    float4 xb0 = Wxbg[ch * 256 + c * 128 + lane];
    float4 xb1 = Wxbg[ch * 256 + c * 128 + 64 + lane];

    // ---- own-half K MFMA first (fills the publish->poll gap); t=0: h=0
    f32x4 acc0 = {0.f, 0.f, 0.f, 0.f}, acc1 = {0.f, 0.f, 0.f, 0.f};
#pragma unroll
    for (int kx = 0; kx < 4; ++kx) {
      FU a; a.u4 = hfrag[(kown + kx) * 64 + lane];
      acc0 = __builtin_amdgcn_mfma_f32_16x16x32_f16(a.h8, wf0[kx].h8, acc0, 0, 0, 0);
      acc1 = __builtin_amdgcn_mfma_f32_16x16x32_f16(a.h8, wf1[kx].h8, acc1, 0, 0, 0);
    }

    if (t > 0) {
      // ---- fused detect+gather: L2 poll with agent escalation
      const int par = t & 1;
      const unsigned long long* src =
          &hx2[((par * 64 + g) * 2 + cs) * 1024 + tid];
      unsigned long long v = poll_tagged(src, (unsigned)t);
      HP hv; hv.u = (unsigned)v;
      const int r = tid >> 6, up = tid & 63;
      const int ka = cs * 128 + up;
      *(_Float16*)((char*)hfrag + afrag_addr(ka,      r)) = hv.f[0];
      *(_Float16*)((char*)hfrag + afrag_addr(ka + 64, r)) = hv.f[1];
      __syncthreads();
    }

    // ---- sibling-half K MFMA
#pragma unroll
    for (int kx = 0; kx < 4; ++kx) {
      FU a; a.u4 = hfrag[(ksib + kx) * 64 + lane];
      acc0 = __builtin_amdgcn_mfma_f32_16x16x32_f16(a.h8, wf0[4 + kx].h8, acc0, 0, 0, 0);
      acc1 = __builtin_amdgcn_mfma_f32_16x16x32_f16(a.h8, wf1[4 + kx].h8, acc1, 0, 0, 0);
    }
    {
      const int cq = lane >> 4, cn = lane & 15;   // C: row=(lane>>4)*4+reg
#pragma unroll
      for (int reg = 0; reg < 4; ++reg) {
        zbuf[(cq * 4 + reg) * ZS + (wv * 2)     * 16 + cn] = acc0[reg];
        zbuf[(cq * 4 + reg) * ZS + (wv * 2 + 1) * 16 + cn] = acc1[reg];
      }
    }
    __syncthreads();   // zbuf ready

    // ---- gates: thread = (row wv, units u0 = c*128+lane, u1 = u0+64)
    {
      float4 z0 = *(const float4*)&zbuf[wv * ZS + lane * 4];
      float4 z1 = *(const float4*)&zbuf[wv * ZS + lane * 4 + 256];
      float i0 = sigm(z0.x + xb0.x), f0 = sigm(z0.y + xb0.y);
      float g0 = tanhx(z0.z + xb0.z), o0 = sigm(z0.w + xb0.w);
      cst0 = f0 * cst0 + i0 * g0;
      float h0 = o0 * tanhx(cst0);
      float i1 = sigm(z1.x + xb1.x), f1 = sigm(z1.y + xb1.y);
      float g1 = tanhx(z1.z + xb1.z), o1 = sigm(z1.w + xb1.w);
      cst1 = f1 * cst1 + i1 * g1;
      float h1 = o1 * tanhx(cst1);

      HP p; p.f[0] = (_Float16)h0; p.f[1] = (_Float16)h1;
      // own half straight to own-kk A-frags
      const int ka = c * 128 + lane;
      *(_Float16*)((char*)hfrag + afrag_addr(ka,      wv)) = p.f[0];
      *(_Float16*)((char*)hfrag + afrag_addr(ka + 64, wv)) = p.f[1];
      // publish tagged payload: agent-scope (cross-XCD correct; updates
      // the shared local L2 on the write-through path)
      const int par1 = (t + 1) & 1;
      unsigned long long val =
          ((unsigned long long)(unsigned)(t + 1) << 32) | (unsigned long long)p.u;
      __hip_atomic_store(&hx2[((par1 * 64 + g) * 2 + c) * 1024 + tid], val,
                         __ATOMIC_RELAXED, __HIP_MEMORY_SCOPE_AGENT);
    }
    __syncthreads();   // hfrag own-half + zbuf handoff for next iteration
  }

  if (c != 0) return;

  // ---- Epilogue (c==0): poll h_T (tag==TSTEPS, par=0) -> fp32, Wd, softmax
  {
    const int r = tid >> 6, up = tid & 63;
#pragma unroll
    for (int half = 0; half < 2; ++half) {
      const unsigned long long* src = &hx2[(g * 2 + half) * 1024 + tid];
      unsigned long long v = poll_tagged(src, (unsigned)TSTEPS);
      HP hv; hv.u = (unsigned)v;
      zbuf[r * ZS + half * 128 + up]      = (float)hv.f[0];
      zbuf[r * ZS + half * 128 + up + 64] = (float)hv.f[1];
    }
  }
  __syncthreads();
  {
    const int j  = tid & 127;
    const int rb = tid >> 7;            // 0..7 -> rows 2rb, 2rb+1
    const int r0 = rb * 2, r1 = r0 + 1;
    float l0 = bd[j], l1 = bd[j];
    for (int k = 0; k < 256; ++k) {
      float w = Wd[k * NCHAR + j];
      l0 += zbuf[r0 * ZS + k] * w;
      l1 += zbuf[r1 * ZS + k] * w;
    }
    lgts[r0 * 132 + j] = l0;
    lgts[r1 * 132 + j] = l1;
  }
  __syncthreads();
  if (tid < 16) {
    const int r = tid;
    float m = -1e30f;
    for (int j = 0; j < NCHAR; ++j) m = fmaxf(m, lgts[r * 132 + j]);
    float s = 0.f;
    for (int j = 0; j < NCHAR; ++j) s += __expf(lgts[r * 132 + j] - m);
    rmax[r] = m;
    rsum[r] = fast_rcp(s);
  }
  __syncthreads();
  {
    const int j  = tid & 127;
    const int rb = tid >> 7;
#pragma unroll
    for (int ii = 0; ii < 2; ++ii) {
      int r = rb * 2 + ii;
      out[(row0 + r) * NCHAR + j] = __expf(lgts[r * 132 + j] - rmax[r]) * rsum[r];
    }
  }
}

extern "C" void kernel_launch(void* const* d_in, const int* in_sizes, int n_in,
                              void* d_out, int out_size, void* d_ws, size_t ws_size,
                              hipStream_t stream) {
  const int*   inp = (const int*)d_in[0];
  const float* Wx  = (const float*)d_in[1];
  const float* Wh  = (const float*)d_in[2];
  const float* bia = (const float*)d_in[3];
  const float* Wd  = (const float*)d_in[4];
  const float* bd  = (const float*)d_in[5];

  uint4*              WhB  = (uint4*)d_ws;                          // 512 KB
  float4*             Wxbg = (float4*)((char*)d_ws + (512 << 10));  // 512 KB
  unsigned long long* hx2  = (unsigned long long*)((char*)d_ws + (1 << 20)); // 2 MB

  prep_whB<<<128, 256, 0, stream>>>(Wh, WhB);
  prep_wx<<<128, 256, 0, stream>>>(Wx, bia, Wxbg);
  lstm_mfma<<<128, 1024, 0, stream>>>(inp, WhB, Wxbg, Wd, bd, (float*)d_out,
                                      hx2);
}